// Round 2
// baseline (82.039 us; speedup 1.0000x reference)
//
#include <hip/hip_runtime.h>
#include <hip/hip_bf16.h>
#include <math.h>

#define HWV (1080 * 1920)
#define NPIX (2 * HWV)
#define GRP_PER_IMG (HWV / 4)   // 518400 groups of 4 pixels
#define ROW_GRP 480             // 1920/4

// ---------------------------------------------------------------------------
// Prep kernel: transpose grid (n,c,z,y,x) -> (n,y,x,z,c) and fold BN.
// ---------------------------------------------------------------------------
__global__ void prep_kernel(const float* __restrict__ grid,
                            const float* __restrict__ w1,
                            const float* __restrict__ b1,
                            const float* __restrict__ gamma,
                            const float* __restrict__ beta,
                            const float* __restrict__ mean,
                            const float* __restrict__ var,
                            const float* __restrict__ w2,
                            const float* __restrict__ b2,
                            float* __restrict__ wsg,   // 49152 floats
                            float* __restrict__ wsw) { // 81 floats
    int i = blockIdx.x * blockDim.x + threadIdx.x;
    if (i < 2 * 12 * 8 * 16 * 16) {
        int c = i % 12;
        int t = i / 12;
        int z = t % 8;  t /= 8;
        int x = t % 16; t /= 16;
        int y = t % 16;
        int n = t / 16;
        wsg[i] = grid[n * 24576 + c * 2048 + z * 256 + y * 16 + x];
    }
    if (i < 16) {
        float inv = gamma[i] / sqrtf(var[i] + 1e-5f);
        wsw[i]      = w1[i * 3 + 0] * inv;
        wsw[16 + i] = w1[i * 3 + 1] * inv;
        wsw[32 + i] = w1[i * 3 + 2] * inv;
        wsw[48 + i] = (b1[i] - mean[i]) * inv + beta[i];
        wsw[64 + i] = w2[i];
    }
    if (i == 0) wsw[80] = b2[0];
}

// ---------------------------------------------------------------------------
// Fused kernel: 4 consecutive pixels (same row) per thread.
// ---------------------------------------------------------------------------
__global__ __launch_bounds__(256) void fused_kernel(
        const float* __restrict__ fullres,
        const float* __restrict__ wsg,
        const float* __restrict__ wsw,
        float* __restrict__ out) {
    int gidx = blockIdx.x * 256 + threadIdx.x;   // group index, exact cover
    int n  = gidx / GRP_PER_IMG;
    int gi = gidx - n * GRP_PER_IMG;
    int y  = gi / ROW_GRP;
    int xg = gi - y * ROW_GRP;
    int p  = y * 1920 + xg * 4;

    const float* fr = fullres + n * 3 * HWV + p;
    float4 R = *(const float4*)(fr);
    float4 G = *(const float4*)(fr + HWV);
    float4 B = *(const float4*)(fr + 2 * HWV);
    float rr[4] = {R.x, R.y, R.z, R.w};
    float gg[4] = {G.x, G.y, G.z, G.w};
    float bb[4] = {B.x, B.y, B.z, B.w};

    // ---- guide MLP (weights via uniform/scalar loads) ----
    float b2s = wsw[80];
    float acc[4] = {b2s, b2s, b2s, b2s};
#pragma unroll
    for (int c = 0; c < 16; ++c) {
        float wr = wsw[c];
        float wg = wsw[16 + c];
        float wb = wsw[32 + c];
        float bs = wsw[48 + c];
        float v2 = wsw[64 + c];
#pragma unroll
        for (int j = 0; j < 4; ++j) {
            float t = fmaf(wr, rr[j], fmaf(wg, gg[j], fmaf(wb, bb[j], bs)));
            t = fmaxf(t, 0.0f);
            acc[j] = fmaf(v2, t, acc[j]);
        }
    }

    // ---- shared y interpolation ----
    float gy = (float)y * (15.0f / 1079.0f);
    float y0f = floorf(gy);
    float ty = gy - y0f;
    int y0 = (int)y0f;
    int y1 = min(y0 + 1, 15);
    float wy0 = 1.0f - ty, wy1 = ty;

    const float* gbase = wsg + n * (16 * 16 * 8 * 12);
    const float* rowb0 = gbase + y0 * (16 * 96);
    const float* rowb1 = gbase + y1 * (16 * 96);

    float outr[4], outg[4], outb[4];

#pragma unroll
    for (int j = 0; j < 4; ++j) {
        // sigmoid -> z coords
        float e = __expf(-acc[j]);
        float guide = __builtin_amdgcn_rcpf(1.0f + e);
        float gz = guide * 7.0f;
        float z0f = floorf(gz);
        float tz = gz - z0f;
        int z0 = min((int)z0f, 7);
        int z1 = min(z0 + 1, 7);

        int x = p - y * 1920 + j;   // = xg*4 + j
        float gx = (float)x * (15.0f / 1919.0f);
        float x0f = floorf(gx);
        float tx = gx - x0f;
        int x0 = (int)x0f;
        int x1 = min(x0 + 1, 15);

        float wx0 = 1.0f - tx, wx1 = tx;
        float wz0 = 1.0f - tz, wz1 = tz;

        float w00 = wy0 * wx0, w01 = wy0 * wx1;
        float w10 = wy1 * wx0, w11 = wy1 * wx1;

        const float* c00 = rowb0 + x0 * 96;
        const float* c01 = rowb0 + x1 * 96;
        const float* c10 = rowb1 + x0 * 96;
        const float* c11 = rowb1 + x1 * 96;

        float co[12];
#pragma unroll
        for (int c = 0; c < 12; ++c) co[c] = 0.0f;

#pragma unroll
        for (int cell = 0; cell < 4; ++cell) {
            const float* cb = (cell == 0) ? c00 : (cell == 1) ? c01 : (cell == 2) ? c10 : c11;
            float wxy = (cell == 0) ? w00 : (cell == 1) ? w01 : (cell == 2) ? w10 : w11;
#pragma unroll
            for (int jz = 0; jz < 2; ++jz) {
                float w = wxy * ((jz == 0) ? wz0 : wz1);
                const float4* p4 = (const float4*)(cb + ((jz == 0) ? z0 : z1) * 12);
                float4 a = p4[0];
                float4 d = p4[1];
                float4 e4 = p4[2];
                co[0]  = fmaf(w, a.x, co[0]);
                co[1]  = fmaf(w, a.y, co[1]);
                co[2]  = fmaf(w, a.z, co[2]);
                co[3]  = fmaf(w, a.w, co[3]);
                co[4]  = fmaf(w, d.x, co[4]);
                co[5]  = fmaf(w, d.y, co[5]);
                co[6]  = fmaf(w, d.z, co[6]);
                co[7]  = fmaf(w, d.w, co[7]);
                co[8]  = fmaf(w, e4.x, co[8]);
                co[9]  = fmaf(w, e4.y, co[9]);
                co[10] = fmaf(w, e4.z, co[10]);
                co[11] = fmaf(w, e4.w, co[11]);
            }
        }

        outr[j] = fmaf(co[0], rr[j], fmaf(co[1], gg[j], fmaf(co[2],  bb[j], co[3])));
        outg[j] = fmaf(co[4], rr[j], fmaf(co[5], gg[j], fmaf(co[6],  bb[j], co[7])));
        outb[j] = fmaf(co[8], rr[j], fmaf(co[9], gg[j], fmaf(co[10], bb[j], co[11])));
    }

    float* op = out + n * 3 * HWV + p;
    *(float4*)(op)           = make_float4(outr[0], outr[1], outr[2], outr[3]);
    *(float4*)(op + HWV)     = make_float4(outg[0], outg[1], outg[2], outg[3]);
    *(float4*)(op + 2 * HWV) = make_float4(outb[0], outb[1], outb[2], outb[3]);
}

extern "C" void kernel_launch(void* const* d_in, const int* in_sizes, int n_in,
                              void* d_out, int out_size, void* d_ws, size_t ws_size,
                              hipStream_t stream) {
    const float* fullres = (const float*)d_in[0];
    const float* grid    = (const float*)d_in[1];
    const float* w1      = (const float*)d_in[2];
    const float* b1      = (const float*)d_in[3];
    const float* gamma   = (const float*)d_in[4];
    const float* beta    = (const float*)d_in[5];
    const float* mean    = (const float*)d_in[6];
    const float* var     = (const float*)d_in[7];
    const float* w2      = (const float*)d_in[8];
    const float* b2      = (const float*)d_in[9];
    float* out = (float*)d_out;

    float* wsg = (float*)d_ws;
    float* wsw = wsg + 49152;

    prep_kernel<<<192, 256, 0, stream>>>(grid, w1, b1, gamma, beta, mean, var,
                                         w2, b2, wsg, wsw);

    int groups = NPIX / 4;              // 1036800
    int blocks = groups / 256;          // 4050 exactly
    fused_kernel<<<blocks, 256, 0, stream>>>(fullres, wsg, wsw, out);
}

// Round 3
// 59.909 us; speedup vs baseline: 1.3694x; 1.3694x over previous
//
#include <hip/hip_runtime.h>
#include <hip/hip_bf16.h>
#include <math.h>

#define HWV (1080 * 1920)
#define NPIX (2 * HWV)

// ---------------------------------------------------------------------------
// Prep kernel: transpose grid (n,c,z,y,x) -> (n,y,x,z,c) and fold BN.
// ---------------------------------------------------------------------------
__global__ void prep_kernel(const float* __restrict__ grid,
                            const float* __restrict__ w1,
                            const float* __restrict__ b1,
                            const float* __restrict__ gamma,
                            const float* __restrict__ beta,
                            const float* __restrict__ mean,
                            const float* __restrict__ var,
                            const float* __restrict__ w2,
                            const float* __restrict__ b2,
                            float* __restrict__ wsg,   // 49152 floats
                            float* __restrict__ wsw) { // 81 floats
    int i = blockIdx.x * blockDim.x + threadIdx.x;
    if (i < 2 * 12 * 8 * 16 * 16) {
        int c = i % 12;
        int t = i / 12;
        int z = t % 8;  t /= 8;
        int x = t % 16; t /= 16;
        int y = t % 16;
        int n = t / 16;
        wsg[i] = grid[n * 24576 + c * 2048 + z * 256 + y * 16 + x];
    }
    if (i < 16) {
        float inv = gamma[i] / sqrtf(var[i] + 1e-5f);
        wsw[i]      = w1[i * 3 + 0] * inv;
        wsw[16 + i] = w1[i * 3 + 1] * inv;
        wsw[32 + i] = w1[i * 3 + 2] * inv;
        wsw[48 + i] = (b1[i] - mean[i]) * inv + beta[i];
        wsw[64 + i] = w2[i];
    }
    if (i == 0) wsw[80] = b2[0];
}

// ---------------------------------------------------------------------------
// Fused kernel: 1 pixel/thread, weights via uniform (scalarized) loads.
// ---------------------------------------------------------------------------
__global__ __launch_bounds__(256) void fused_kernel(
        const float* __restrict__ fullres,
        const float* __restrict__ wsg,
        const float* __restrict__ wsw,
        float* __restrict__ out) {
    int i = blockIdx.x * 256 + threadIdx.x;   // exact cover: 16200*256 = NPIX
    int n = i / HWV;
    int p = i - n * HWV;
    int y = p / 1920;
    int x = p - y * 1920;

    const float* fr = fullres + n * 3 * HWV + p;
    float r = fr[0];
    float g = fr[HWV];
    float b = fr[2 * HWV];

    // ---- guide MLP (BN folded; weights are wave-uniform -> SGPRs) ----
    float acc = wsw[80];
#pragma unroll
    for (int c = 0; c < 16; ++c) {
        float t = fmaf(wsw[c], r,
                  fmaf(wsw[16 + c], g,
                  fmaf(wsw[32 + c], b, wsw[48 + c])));
        t = fmaxf(t, 0.0f);
        acc = fmaf(wsw[64 + c], t, acc);
    }
    // sigmoid via fast exp + rcp
    float e = __expf(-acc);
    float guide = __builtin_amdgcn_rcpf(1.0f + e);

    // ---- interpolation coordinates ----
    float gz = guide * 7.0f;
    float z0f = floorf(gz);
    float tz = gz - z0f;
    int z0 = min((int)z0f, 7);
    int z1 = min(z0 + 1, 7);

    float gy = (float)y * (15.0f / 1079.0f);
    float y0f = floorf(gy);
    float ty = gy - y0f;
    int y0 = (int)y0f;
    int y1 = min(y0 + 1, 15);

    float gx = (float)x * (15.0f / 1919.0f);
    float x0f = floorf(gx);
    float tx = gx - x0f;
    int x0 = (int)x0f;
    int x1 = min(x0 + 1, 15);

    float wyv[2] = {1.0f - ty, ty};  int ysv[2] = {y0, y1};
    float wxv[2] = {1.0f - tx, tx};  int xsv[2] = {x0, x1};
    float wzv[2] = {1.0f - tz, tz};  int zsv[2] = {z0, z1};

    float co[12];
#pragma unroll
    for (int c = 0; c < 12; ++c) co[c] = 0.0f;

    const float* gbase = wsg + n * (16 * 16 * 8 * 12);
#pragma unroll
    for (int jy = 0; jy < 2; ++jy) {
#pragma unroll
        for (int jx = 0; jx < 2; ++jx) {
            float wxy = wyv[jy] * wxv[jx];
            const float* cb = gbase + (ysv[jy] * 16 + xsv[jx]) * 96;
#pragma unroll
            for (int jz = 0; jz < 2; ++jz) {
                float w = wxy * wzv[jz];
                const float4* p4 = (const float4*)(cb + zsv[jz] * 12);
                float4 a  = p4[0];
                float4 d  = p4[1];
                float4 e4 = p4[2];
                co[0]  = fmaf(w, a.x,  co[0]);
                co[1]  = fmaf(w, a.y,  co[1]);
                co[2]  = fmaf(w, a.z,  co[2]);
                co[3]  = fmaf(w, a.w,  co[3]);
                co[4]  = fmaf(w, d.x,  co[4]);
                co[5]  = fmaf(w, d.y,  co[5]);
                co[6]  = fmaf(w, d.z,  co[6]);
                co[7]  = fmaf(w, d.w,  co[7]);
                co[8]  = fmaf(w, e4.x, co[8]);
                co[9]  = fmaf(w, e4.y, co[9]);
                co[10] = fmaf(w, e4.z, co[10]);
                co[11] = fmaf(w, e4.w, co[11]);
            }
        }
    }

    // ---- apply coeffs ----
    float* op = out + n * 3 * HWV + p;
    op[0]       = fmaf(co[0], r, fmaf(co[1], g, fmaf(co[2],  b, co[3])));
    op[HWV]     = fmaf(co[4], r, fmaf(co[5], g, fmaf(co[6],  b, co[7])));
    op[2 * HWV] = fmaf(co[8], r, fmaf(co[9], g, fmaf(co[10], b, co[11])));
}

extern "C" void kernel_launch(void* const* d_in, const int* in_sizes, int n_in,
                              void* d_out, int out_size, void* d_ws, size_t ws_size,
                              hipStream_t stream) {
    const float* fullres = (const float*)d_in[0];
    const float* grid    = (const float*)d_in[1];
    const float* w1      = (const float*)d_in[2];
    const float* b1      = (const float*)d_in[3];
    const float* gamma   = (const float*)d_in[4];
    const float* beta    = (const float*)d_in[5];
    const float* mean    = (const float*)d_in[6];
    const float* var     = (const float*)d_in[7];
    const float* w2      = (const float*)d_in[8];
    const float* b2      = (const float*)d_in[9];
    float* out = (float*)d_out;

    float* wsg = (float*)d_ws;
    float* wsw = wsg + 49152;

    prep_kernel<<<192, 256, 0, stream>>>(grid, w1, b1, gamma, beta, mean, var,
                                         w2, b2, wsg, wsw);

    int blocks = NPIX / 256;    // 16200 exactly
    fused_kernel<<<blocks, 256, 0, stream>>>(fullres, wsg, wsw, out);
}

// Round 4
// 39.008 us; speedup vs baseline: 2.1032x; 1.5358x over previous
//
#include <hip/hip_runtime.h>
#include <hip/hip_bf16.h>
#include <math.h>

#define HWV (1080 * 1920)
#define NPIX (2 * HWV)

// ---------------------------------------------------------------------------
// Prep kernel: transpose grid (n,c,z,y,x) -> (n,y,x,z,c) and fold BN.
// ---------------------------------------------------------------------------
__global__ void prep_kernel(const float* __restrict__ grid,
                            const float* __restrict__ w1,
                            const float* __restrict__ b1,
                            const float* __restrict__ gamma,
                            const float* __restrict__ beta,
                            const float* __restrict__ mean,
                            const float* __restrict__ var,
                            const float* __restrict__ w2,
                            const float* __restrict__ b2,
                            float* __restrict__ wsg,   // 49152 floats
                            float* __restrict__ wsw) { // 81 floats
    int i = blockIdx.x * blockDim.x + threadIdx.x;
    if (i < 2 * 12 * 8 * 16 * 16) {
        int c = i % 12;
        int t = i / 12;
        int z = t % 8;  t /= 8;
        int x = t % 16; t /= 16;
        int y = t % 16;
        int n = t / 16;
        wsg[i] = grid[n * 24576 + c * 2048 + z * 256 + y * 16 + x];
    }
    if (i < 16) {
        float inv = gamma[i] / sqrtf(var[i] + 1e-5f);
        wsw[i]      = w1[i * 3 + 0] * inv;
        wsw[16 + i] = w1[i * 3 + 1] * inv;
        wsw[32 + i] = w1[i * 3 + 2] * inv;
        wsw[48 + i] = (b1[i] - mean[i]) * inv + beta[i];
        wsw[64 + i] = w2[i];
    }
    if (i == 0) wsw[80] = b2[0];
}

// ---------------------------------------------------------------------------
// Fused kernel. Block = 256 threads = 2 rows x 128 px. Stage the block's
// (<=3 x-cells) of the grid into LDS, ALREADY y-interpolated (ty is
// row-uniform). Per pixel: bilinear (x,z) over 4 slices from LDS.
// ---------------------------------------------------------------------------
__global__ __launch_bounds__(256) void fused_kernel(
        const float* __restrict__ fullres,
        const float* __restrict__ wsg,
        const float* __restrict__ wsw,
        float* __restrict__ out) {
    __shared__ float sg[2][288];   // 2 rows x 3 cells x (8z * 12c)

    const int tid = threadIdx.x;
    const int n   = blockIdx.z;
    const int ypair = blockIdx.y * 2;
    const int xs  = blockIdx.x * 128;

    // leftmost x-cell of this segment (same formula as per-pixel x0)
    const int a = (int)((float)xs * (15.0f / 1919.0f));
    const float* gbase = wsg + n * 24576;

    // ---- stage: 2 rows x 3 cells x 96 floats, y-lerped ----
    for (int idx = tid; idx < 576; idx += 256) {
        int row = idx / 288;
        int rem = idx - row * 288;
        int k = rem / 96;
        int f = rem - k * 96;
        int y = ypair + row;
        float gy = (float)y * (15.0f / 1079.0f);
        float y0f = floorf(gy);
        float ty = gy - y0f;
        int y0 = min((int)y0f, 15);
        int y1 = min(y0 + 1, 15);
        int xc = min(a + k, 15);
        float g0 = gbase[(y0 * 16 + xc) * 96 + f];
        float g1 = gbase[(y1 * 16 + xc) * 96 + f];
        sg[row][rem] = fmaf(ty, g1 - g0, g0);
    }
    __syncthreads();

    const int row = tid >> 7;          // wave-uniform
    const int lx  = tid & 127;
    const int x   = xs + lx;
    const int y   = ypair + row;
    const int p   = y * 1920 + x;

    const float* fr = fullres + n * 3 * HWV + p;
    float r = fr[0];
    float g = fr[HWV];
    float b = fr[2 * HWV];

    // ---- guide MLP (weights wave-uniform -> s_loads) ----
    float acc = wsw[80];
#pragma unroll
    for (int c = 0; c < 16; ++c) {
        float t = fmaf(wsw[c], r,
                  fmaf(wsw[16 + c], g,
                  fmaf(wsw[32 + c], b, wsw[48 + c])));
        t = fmaxf(t, 0.0f);
        acc = fmaf(wsw[64 + c], t, acc);
    }
    float e = __expf(-acc);
    float guide = __builtin_amdgcn_rcpf(1.0f + e);

    // ---- coords ----
    float gz = guide * 7.0f;
    float z0f = floorf(gz);
    float tz = gz - z0f;
    int z0 = min((int)z0f, 7);
    int z1 = min(z0 + 1, 7);

    float gx = (float)x * (15.0f / 1919.0f);
    float x0f = floorf(gx);
    float tx = gx - x0f;
    int x0 = min((int)x0f, 15);
    int x1 = min(x0 + 1, 15);
    int k0 = x0 - a;                   // 0..2
    int k1 = x1 - a;                   // 0..2

    float wx0 = 1.0f - tx, wx1 = tx;
    float wz0 = 1.0f - tz, wz1 = tz;
    float w00 = wx0 * wz0, w01 = wx0 * wz1;
    float w10 = wx1 * wz0, w11 = wx1 * wz1;

    const float* s = sg[row];
    const float4* s00 = (const float4*)(s + k0 * 96 + z0 * 12);
    const float4* s01 = (const float4*)(s + k0 * 96 + z1 * 12);
    const float4* s10 = (const float4*)(s + k1 * 96 + z0 * 12);
    const float4* s11 = (const float4*)(s + k1 * 96 + z1 * 12);

    float co[12];
#pragma unroll
    for (int c = 0; c < 12; ++c) co[c] = 0.0f;

#pragma unroll
    for (int q = 0; q < 3; ++q) {
        float4 v00 = s00[q];
        float4 v01 = s01[q];
        float4 v10 = s10[q];
        float4 v11 = s11[q];
        co[q*4+0] = fmaf(w00, v00.x, fmaf(w01, v01.x, fmaf(w10, v10.x, fmaf(w11, v11.x, co[q*4+0]))));
        co[q*4+1] = fmaf(w00, v00.y, fmaf(w01, v01.y, fmaf(w10, v10.y, fmaf(w11, v11.y, co[q*4+1]))));
        co[q*4+2] = fmaf(w00, v00.z, fmaf(w01, v01.z, fmaf(w10, v10.z, fmaf(w11, v11.z, co[q*4+2]))));
        co[q*4+3] = fmaf(w00, v00.w, fmaf(w01, v01.w, fmaf(w10, v10.w, fmaf(w11, v11.w, co[q*4+3]))));
    }

    // ---- apply coeffs ----
    float* op = out + n * 3 * HWV + p;
    op[0]       = fmaf(co[0], r, fmaf(co[1], g, fmaf(co[2],  b, co[3])));
    op[HWV]     = fmaf(co[4], r, fmaf(co[5], g, fmaf(co[6],  b, co[7])));
    op[2 * HWV] = fmaf(co[8], r, fmaf(co[9], g, fmaf(co[10], b, co[11])));
}

extern "C" void kernel_launch(void* const* d_in, const int* in_sizes, int n_in,
                              void* d_out, int out_size, void* d_ws, size_t ws_size,
                              hipStream_t stream) {
    const float* fullres = (const float*)d_in[0];
    const float* grid    = (const float*)d_in[1];
    const float* w1      = (const float*)d_in[2];
    const float* b1      = (const float*)d_in[3];
    const float* gamma   = (const float*)d_in[4];
    const float* beta    = (const float*)d_in[5];
    const float* mean    = (const float*)d_in[6];
    const float* var     = (const float*)d_in[7];
    const float* w2      = (const float*)d_in[8];
    const float* b2      = (const float*)d_in[9];
    float* out = (float*)d_out;

    float* wsg = (float*)d_ws;
    float* wsw = wsg + 49152;

    prep_kernel<<<192, 256, 0, stream>>>(grid, w1, b1, gamma, beta, mean, var,
                                         w2, b2, wsg, wsw);

    dim3 grid_dim(1920 / 128, 1080 / 2, 2);   // 15 x 540 x 2 = 16200 blocks
    fused_kernel<<<grid_dim, 256, 0, stream>>>(fullres, wsg, wsw, out);
}